// Round 3
// baseline (433.251 us; speedup 1.0000x reference)
//
#include <hip/hip_runtime.h>

// EpistemicQuantizer — primal-only:
//   out0 = codebook[argmax_j (x . cbn_j)]  (raw codebook rows)
//   out1 = argmax indices (as float32 values)
// gumbel_noise input is numerically dead for the primal outputs -> never read.
//
// Grid = 256 rowblocks x 4 V-chunks = 1024 blocks; 34.8 KB LDS -> exactly
// 4 blocks/CU (16 waves/CU), one dispatch round, no ragged tail.
// Staging is T14-split: next tile's global loads issued before compute.

constexpr int N_ROWS = 16384;     // B*T
constexpr int D      = 64;
constexpr int V      = 4096;
constexpr int BM     = 64;        // rows per block
constexpr int BN     = 64;        // codes per LDS tile
constexpr int NCH    = 4;         // V chunks
constexpr int VCHUNK = V / NCH;   // 1024
constexpr int NT     = VCHUNK / BN; // 16 tiles per block
constexpr int LS     = 68;        // padded LDS row stride (floats)

__global__ __launch_bounds__(256) void normalize_cb(const float* __restrict__ cb,
                                                    float* __restrict__ cbn) {
    int g = blockIdx.x * 256 + threadIdx.x;   // 65536 threads: 16 per row
    int row = g >> 4, part = g & 15;
    float4 v = *reinterpret_cast<const float4*>(cb + row * D + part * 4);
    float ss = v.x * v.x + v.y * v.y + v.z * v.z + v.w * v.w;
    ss += __shfl_xor(ss, 1);
    ss += __shfl_xor(ss, 2);
    ss += __shfl_xor(ss, 4);
    ss += __shfl_xor(ss, 8);
    float inv = 1.0f / fmaxf(sqrtf(ss), 1e-12f);
    *reinterpret_cast<float4*>(cbn + row * D + part * 4) =
        make_float4(v.x * inv, v.y * inv, v.z * inv, v.w * inv);
}

__global__ __launch_bounds__(256, 4) void quantize(const float* __restrict__ x,
                                                   const float* __restrict__ cbn,
                                                   float* __restrict__ pv,
                                                   int* __restrict__ pi) {
    __shared__ float xs[BM * LS];   // 64 x 68 floats = 17408 B
    __shared__ float bs[BN * LS];   // 64 x 68 floats = 17408 B (total 34816 -> 4 blocks/CU)
    const int tid = threadIdx.x;
    const int tc = tid & 15;        // code-group 0..15
    const int tr = tid >> 4;        // row-group 0..15
    const int rowblk = blockIdx.x & (N_ROWS / BM - 1);  // 0..255
    const int chunk  = blockIdx.x >> 8;                 // 0..3
    const int row0  = rowblk * BM;
    const int vbase = chunk * VCHUNK;

    // stage x tile: 64 rows x 64 floats (1024 float4), coalesced
#pragma unroll
    for (int p = 0; p < 4; ++p) {
        int f = p * 256 + tid;
        int r = f >> 4, k4 = f & 15;
        float4 v = *reinterpret_cast<const float4*>(x + row0 * D + f * 4);
        *reinterpret_cast<float4*>(&xs[r * LS + k4 * 4]) = v;
    }

    // prologue: tile 0 of this chunk -> staging regs
    float4 st[4];
#pragma unroll
    for (int p = 0; p < 4; ++p) {
        int f = p * 256 + tid;
        st[p] = *reinterpret_cast<const float4*>(cbn + vbase * D + f * 4);
    }

    float best_v[4];
    int   best_c[4];                // code minus tc (uniform per (t,n) -> cheap cndmask)
#pragma unroll
    for (int m = 0; m < 4; ++m) { best_v[m] = -1e30f; best_c[m] = 0; }

    for (int t = 0; t < NT; ++t) {
        __syncthreads();  // tile t-1 readers done (t==0: xs staging ordering)
#pragma unroll
        for (int p = 0; p < 4; ++p) {
            int f = p * 256 + tid;
            int r = f >> 4, k4 = f & 15;
            *reinterpret_cast<float4*>(&bs[r * LS + k4 * 4]) = st[p];
        }
        __syncthreads();

        // issue next tile's global loads now; latency hides under compute (T14)
        if (t + 1 < NT) {
#pragma unroll
            for (int p = 0; p < 4; ++p) {
                int f = p * 256 + tid;
                st[p] = *reinterpret_cast<const float4*>(cbn + (vbase + (t + 1) * BN) * D + f * 4);
            }
        }

        float acc[4][4];
#pragma unroll
        for (int m = 0; m < 4; ++m)
#pragma unroll
            for (int n = 0; n < 4; ++n) acc[m][n] = 0.f;

#pragma unroll
        for (int kk = 0; kk < D; kk += 4) {
            float4 a[4], b[4];
#pragma unroll
            for (int m = 0; m < 4; ++m)
                a[m] = *reinterpret_cast<const float4*>(&xs[(tr + 16 * m) * LS + kk]);
#pragma unroll
            for (int n = 0; n < 4; ++n)
                b[n] = *reinterpret_cast<const float4*>(&bs[(tc + 16 * n) * LS + kk]);
#pragma unroll
            for (int m = 0; m < 4; ++m)
#pragma unroll
                for (int n = 0; n < 4; ++n) {
                    acc[m][n] = fmaf(a[m].x, b[n].x, acc[m][n]);
                    acc[m][n] = fmaf(a[m].y, b[n].y, acc[m][n]);
                    acc[m][n] = fmaf(a[m].z, b[n].z, acc[m][n]);
                    acc[m][n] = fmaf(a[m].w, b[n].w, acc[m][n]);
                }
        }

        // running best; codes ascend with t and n, strict '>' keeps lowest index
#pragma unroll
        for (int m = 0; m < 4; ++m)
#pragma unroll
            for (int n = 0; n < 4; ++n) {
                int cpr = vbase + t * BN + 16 * n;   // uniform across lanes
                if (acc[m][n] > best_v[m]) { best_v[m] = acc[m][n]; best_c[m] = cpr; }
            }
    }

    // cross-thread argmax over the 16 column-groups (stride 17 avoids conflicts)
    __syncthreads();
    float* rv = xs;                                   // [64][17]
    int*   ri = reinterpret_cast<int*>(xs + BM * 17); // [64][17]
#pragma unroll
    for (int m = 0; m < 4; ++m) {
        int row = tr + 16 * m;
        rv[row * 17 + tc] = best_v[m];
        ri[row * 17 + tc] = best_c[m] + tc;           // restore true code
    }
    __syncthreads();
    if (tid < BM) {
        float bv = rv[tid * 17];
        int   bi = ri[tid * 17];
#pragma unroll
        for (int c = 1; c < 16; ++c) {
            float v = rv[tid * 17 + c];
            int   i = ri[tid * 17 + c];
            if (v > bv || (v == bv && i < bi)) { bv = v; bi = i; }  // first max wins
        }
        pv[chunk * N_ROWS + row0 + tid] = bv;
        pi[chunk * N_ROWS + row0 + tid] = bi;
    }
}

__global__ __launch_bounds__(256) void merge_gather(const float* __restrict__ pv,
                                                    const int* __restrict__ pi,
                                                    const float* __restrict__ cb,
                                                    float* __restrict__ out) {
    int g = blockIdx.x * 256 + threadIdx.x;   // 4 threads per row
    int row = g >> 2, q = g & 3;
    float bv = pv[row];
    int   bi = pi[row];
#pragma unroll
    for (int c = 1; c < NCH; ++c) {
        float v = pv[c * N_ROWS + row];
        int   i = pi[c * N_ROWS + row];
        if (v > bv) { bv = v; bi = i; }  // ascending chunks: strict '>' keeps lowest index
    }
    if (q == 0) out[N_ROWS * D + row] = (float)bi;   // index as float32 value
    const float4* src = reinterpret_cast<const float4*>(cb + bi * D) + q * 4;
    float4*       dst = reinterpret_cast<float4*>(out + row * D) + q * 4;
#pragma unroll
    for (int i = 0; i < 4; ++i) dst[i] = src[i];
}

extern "C" void kernel_launch(void* const* d_in, const int* in_sizes, int n_in,
                              void* d_out, int out_size, void* d_ws, size_t ws_size,
                              hipStream_t stream) {
    const float* x  = (const float*)d_in[0];
    const float* cb = (const float*)d_in[1];
    // d_in[2] (gumbel_noise) intentionally unused: dead for primal outputs
    float* cbn = (float*)d_ws;                                        // 1 MB
    float* pv  = (float*)((char*)d_ws + (size_t)V * D * 4);           // 256 KB
    int*   pi  = (int*)  ((char*)d_ws + (size_t)V * D * 4
                                      + (size_t)NCH * N_ROWS * 4);    // 256 KB
    float* out = (float*)d_out;

    normalize_cb<<<V * 16 / 256, 256, 0, stream>>>(cb, cbn);
    quantize<<<(N_ROWS / BM) * NCH, 256, 0, stream>>>(x, cbn, pv, pi);
    merge_gather<<<N_ROWS * 4 / 256, 256, 0, stream>>>(pv, pi, cb, out);
}